// Round 19
// baseline (3355.299 us; speedup 1.0000x reference)
//
#include <hip/hip_runtime.h>
#include <hip/hip_bf16.h>

using bf16 = __hip_bfloat16;
typedef __attribute__((ext_vector_type(8))) short short8;
typedef __attribute__((ext_vector_type(4))) short s16x4;
typedef __attribute__((ext_vector_type(4))) float f32x4;
typedef __attribute__((ext_vector_type(8))) int i32x8;
typedef __attribute__((ext_vector_type(4))) int i32x4;
typedef __attribute__((ext_vector_type(2))) int i32x2;

#define DEVI __device__ __forceinline__

#define MTOT 16384      // 64 * 16 * 16 output positions
#define PADS 25600      // 64 * 20 * 20 padded positions

DEVI float sigm_(float x){ return 1.f/(1.f+expf(-x)); }

// bf16 (raw short) -> f32: exact 16-bit shift.
DEVI float s2f(short v){
  unsigned u = ((unsigned)(unsigned short)v) << 16;
  return __builtin_bit_cast(float, u);
}
DEVI short f2s(float x){
  bf16 hb = __float2bfloat16(x);
  return __builtin_bit_cast(short, hb);
}

DEVI long pidx_(int m){
  int nb = m>>8, iy=(m>>4)&15, ix=m&15;
  return (long)(nb*20 + iy + 2)*20 + (ix + 2);
}

DEVI unsigned char f2fp8(float x){
  int p = __builtin_amdgcn_cvt_pk_fp8_f32(x, 0.f, 0, false);
  return (unsigned char)(p & 0xFF);
}
DEVI float fp82f(unsigned char v){
  return __builtin_amdgcn_cvt_f32_fp8((int)v, 0);
}
DEVI unsigned pack4fp8(float a, float b, float c, float d){
  int w = __builtin_amdgcn_cvt_pk_fp8_f32(a, b, 0, false);
  w     = __builtin_amdgcn_cvt_pk_fp8_f32(c, d, w, true);
  return (unsigned)w;
}

// async global->LDS, 16B per lane. LDS dest = wave-uniform base + lane*16.
DEVI void async16(const void* g, void* l) {
  __builtin_amdgcn_global_load_lds(
      (__attribute__((address_space(1))) void*)(unsigned long long)g,
      (__attribute__((address_space(3))) void*)(unsigned int)(unsigned long long)l,
      16, 0, 0);
}

// ---------------------------------------------------------------------------
// MX-fp8 GEMM core v2. BM=128, BN=128, BK=128, 4 waves 2Mx2N, double-buffered
// 64KB LDS -> 2 blocks/CU, TRANSPOSED output (operand swap, C^T frag layout).
//
// K layout: grouped per kh-row, row padded to NROW*128 (Kp8 = 5*NROW*128).
// B zero-padded in the pad; A over-reads valid memory x zero weights. This
// fixes the tap-straddle (no subtile crosses a kh row) and makes the staging
// shift advance by +128/subtile (one constant bump per row; NO div/mod).
//
// LDS layout: FRAGMENT-ORDERED. Piece p = tid+256i -> (H=p>>9, blk=(p>>6)&7,
// ln=p&63): trow = H*64 + (blk>>1)*16 + (ln&15), kch = 2*(ln>>4) + (blk&1).
// Wave (wm,wn) then reads its 8 A(B)-fragments as ds_read_b128 at IMMEDIATE
// offsets k*1024 from ONE lane-contiguous base (+ln*16): zero bank conflicts
// by construction, minimal read addressing.
// scale_a=122 (weights x2^5 undone exactly), scale_b=127.
// Runtime subtile range [ns0, ns0+nst) for split-K.
// ---------------------------------------------------------------------------
template<int CA, int NROW>
DEVI void g8_core(const unsigned char* __restrict__ A8,
                  const unsigned char* __restrict__ Bt8,
                  int m0, int n0, unsigned char* AsB, unsigned char* BsB,
                  f32x4 (&acc)[4][4], int ns0, int nst)
{
  constexpr int Kp8 = 5*NROW*128;
  const int tid = threadIdx.x;
  const int wv = tid>>6, ln = tid&63;

  long paA[4], pbB[4];
  #pragma unroll
  for (int i=0;i<4;i++){
    const int p = tid + (i<<8);
    const int H = p>>9, blk = (p>>6)&7, pl = p&63;
    const int trow = (H<<6) + ((blk>>1)<<4) + (pl&15);
    const int kch = ((pl>>4)<<1) + (blk&1);
    const int mA = m0 + trow;
    paA[i] = (long)(((mA>>8)*20 + ((mA>>4)&15))*20 + (mA&15))*CA + kch*16;
    pbB[i] = (long)(n0 + trow)*Kp8 + kch*16;
  }

  int rowc = ns0 % NROW;
  long sh = (long)(ns0/NROW)*20*CA + (long)rowc*128;
  long ks = (long)ns0*128;

  auto stage = [&](int d){
    char* la = (char*)AsB + d*16384 + (wv<<10);
    char* lb = (char*)BsB + d*16384 + (wv<<10);
    #pragma unroll
    for (int i=0;i<4;i++) async16(A8 + paA[i] + sh, la + i*4096);
    #pragma unroll
    for (int i=0;i<4;i++) async16(Bt8 + pbB[i] + ks, lb + i*4096);
    ks += 128;
    sh += 128;
    if (++rowc == NROW){ rowc = 0; sh += 20*CA - NROW*128; }
  };

  const int wm = wv>>1, wn = wv&1;
  const char* ra = (const char*)AsB + (wm<<13) + (ln<<4);
  const char* rb = (const char*)BsB + (wn<<13) + (ln<<4);

  stage(0);
  for (int t=0; t<nst; ++t) {
    asm volatile("s_waitcnt vmcnt(0)\ns_barrier" ::: "memory");
    if (t+1 < nst) stage((t+1)&1);

    const char* as_ = ra + (t&1)*16384;
    const char* bs_ = rb + (t&1)*16384;
    i32x8 af[4], bfr[4];
    #pragma unroll
    for (int f=0; f<4; f++){
      ((i32x4*)&af[f])[0]  = *(const i32x4*)(as_ + (f*2  )*1024);
      ((i32x4*)&af[f])[1]  = *(const i32x4*)(as_ + (f*2+1)*1024);
      ((i32x4*)&bfr[f])[0] = *(const i32x4*)(bs_ + (f*2  )*1024);
      ((i32x4*)&bfr[f])[1] = *(const i32x4*)(bs_ + (f*2+1)*1024);
    }
    __builtin_amdgcn_s_setprio(1);
    #pragma unroll
    for (int bf=0; bf<4; bf++)
      #pragma unroll
      for (int afi=0; afi<4; afi++)
        acc[bf][afi] = __builtin_amdgcn_mfma_scale_f32_16x16x128_f8f6f4(
            bfr[bf], af[afi], acc[bf][afi], 0, 0, 0, 122, 0, 127);
    __builtin_amdgcn_s_setprio(0);
  }
}

// gates GEMM: bf16 out stride 512 + bias; vectorized (C^T) epilogue.
template<int CA, int NROW>
__global__ __launch_bounds__(256)
void conv_g8(const unsigned char* __restrict__ A8,
             const unsigned char* __restrict__ Bt8,
             const float* __restrict__ bias, bf16* __restrict__ outB)
{
  __shared__ alignas(16) unsigned char As[2][16384];
  __shared__ alignas(16) unsigned char Bs[2][16384];
  const int m0 = blockIdx.x<<7, n0 = blockIdx.y<<7;
  f32x4 acc[4][4] = {};
  g8_core<CA,NROW>(A8, Bt8, m0, n0, &As[0][0], &Bs[0][0], acc, 0, 5*NROW);

  const int tid = threadIdx.x;
  const int wv = tid>>6, ln = tid&63;
  const int mb = m0 + ((wv>>1)<<6);
  const int nb = n0 + ((wv&1)<<6);
  const int ml = (ln>>4)<<2;
  const int nl = ln&15;
  #pragma unroll
  for (int bf=0; bf<4; bf++)
    #pragma unroll
    for (int afi=0; afi<4; afi++) {
      const long m = mb + (afi<<4) + nl;
      const int n = nb + (bf<<4) + ml;
      f32x4 b = *(const f32x4*)(bias + n);
      f32x4 v = acc[bf][afi];
      s16x4 o;
      #pragma unroll
      for (int j=0;j<4;j++) o[j] = f2s(v[j] + b[j]);
      *(s16x4*)(outB + (m<<9) + n) = o;
    }
}

// merged fp8 T-convs, vectorized (C^T) epilogues:
// z=0 decT+prior: n<352 -> sDec8 (+TBD+ST) ; n0==384 -> PriorO f32 (+pb)
// z=1 encT:       n<416 -> sEnc8 (+TBE+ST+hDec(n<128))
__global__ __launch_bounds__(256)
void conv_tp8(const unsigned char* __restrict__ h8Dec,
              const unsigned char* __restrict__ h8Enc,
              const unsigned char* __restrict__ Bt8DP,
              const unsigned char* __restrict__ Bt8EncT,
              const float* __restrict__ TBD, const float* __restrict__ prior_b,
              const float* __restrict__ TBE,
              float* __restrict__ PriorO,
              unsigned char* __restrict__ sDec8, const bf16* __restrict__ STdec,
              unsigned char* __restrict__ sEnc8, const bf16* __restrict__ STenc,
              const bf16* __restrict__ hDecB)
{
  __shared__ alignas(16) unsigned char As[2][16384];
  __shared__ alignas(16) unsigned char Bs[2][16384];
  const int z = blockIdx.z;
  const int m0 = blockIdx.x<<7, n0 = blockIdx.y<<7;
  f32x4 acc[4][4] = {};
  if (z == 0) g8_core<128,5>(h8Dec, Bt8DP,   m0, n0, &As[0][0], &Bs[0][0], acc, 0, 25);
  else        g8_core<128,5>(h8Enc, Bt8EncT, m0, n0, &As[0][0], &Bs[0][0], acc, 0, 25);

  const int tid = threadIdx.x;
  const int wv = tid>>6, ln = tid&63;
  const int mb = m0 + ((wv>>1)<<6);
  const int nb = n0 + ((wv&1)<<6);
  const int ml = (ln>>4)<<2;
  const int nl = ln&15;
  #pragma unroll
  for (int afi=0; afi<4; afi++) {
    const long m = mb + (afi<<4) + nl;
    const long pI = pidx_(m);
    #pragma unroll
    for (int bf=0; bf<4; bf++) {
      const int n = nb + (bf<<4) + ml;
      f32x4 v = acc[bf][afi];
      if (z == 0) {
        if (n0 == 384) {            // prior: f32 [m][128] + prior_b
          f32x4 b = *(const f32x4*)(prior_b + (n-384));
          *(f32x4*)(PriorO + (m<<7) + (n-384)) = v + b;
        } else if (n < 352) {       // sDec8 fp8, +tb +ST
          f32x4 tb = *(const f32x4*)(TBD + n);
          s16x4 st = *(const s16x4*)(STdec + m*352 + n);
          float f0 = v[0]+tb[0]+s2f(st[0]);
          float f1 = v[1]+tb[1]+s2f(st[1]);
          float f2 = v[2]+tb[2]+s2f(st[2]);
          float f3 = v[3]+tb[3]+s2f(st[3]);
          *(unsigned*)(sDec8 + pI*352 + n) = pack4fp8(f0,f1,f2,f3);
        }
      } else {
        if (n < 416) {              // sEnc8 fp8, +tb +ST (+hDec if n<128)
          f32x4 tb = *(const f32x4*)(TBE + n);
          s16x4 st = *(const s16x4*)(STenc + m*416 + n);
          float f0 = v[0]+tb[0]+s2f(st[0]);
          float f1 = v[1]+tb[1]+s2f(st[1]);
          float f2 = v[2]+tb[2]+s2f(st[2]);
          float f3 = v[3]+tb[3]+s2f(st[3]);
          if (n < 128) {
            s16x4 e = *(const s16x4*)(hDecB + (pI<<7) + n);
            f0 += s2f(e[0]); f1 += s2f(e[1]); f2 += s2f(e[2]); f3 += s2f(e[3]);
          }
          *(unsigned*)(sEnc8 + pI*416 + n) = pack4fp8(f0,f1,f2,f3);
        }
      }
    }
  }
}

// post GEMM: MX-fp8 split-K=4, bf16 partial planes [z][m][128], C^T epilogue.
__global__ __launch_bounds__(256)
void conv_p8(const unsigned char* __restrict__ h8Enc,
             const unsigned char* __restrict__ Bt8Post,
             bf16* __restrict__ PP)
{
  __shared__ alignas(16) unsigned char As[2][16384];
  __shared__ alignas(16) unsigned char Bs[2][16384];
  const int z = blockIdx.z;
  const int s0[4]  = {0, 7, 13, 19};
  const int len[4] = {7, 6, 6, 6};
  const int m0 = blockIdx.x<<7;
  f32x4 acc[4][4] = {};
  g8_core<128,5>(h8Enc, Bt8Post, m0, 0, &As[0][0], &Bs[0][0], acc, s0[z], len[z]);

  bf16* plane = PP + (long)z*MTOT*128;
  const int tid = threadIdx.x;
  const int wv = tid>>6, ln = tid&63;
  const int mb = m0 + ((wv>>1)<<6);
  const int nb = (wv&1)<<6;
  const int ml = (ln>>4)<<2;
  const int nl = ln&15;
  #pragma unroll
  for (int bf=0; bf<4; bf++)
    #pragma unroll
    for (int afi=0; afi<4; afi++) {
      const long m = mb + (afi<<4) + nl;
      const int n = nb + (bf<<4) + ml;
      f32x4 v = acc[bf][afi];
      s16x4 o;
      #pragma unroll
      for (int j=0;j<4;j++) o[j] = f2s(v[j]);
      *(s16x4*)(plane + (m<<7) + n) = o;
    }
}

// fp8 repack, kh-row-grouped K with row padded to NROW*128 (zeros in pad),
// weights x32 (undone by MFMA scale 2^-5).
__global__ void repack_w8_k(const float* __restrict__ w, unsigned char* __restrict__ Bt,
                            int O, int I, int CA, int NROW, long total)
{
  long e = (long)blockIdx.x*256 + threadIdx.x;
  if (e >= total) return;
  const int RW = NROW*128;
  const int Kp8 = 5*RW;
  int o = (int)(e / Kp8);
  int k = (int)(e % Kp8);
  int kh = k / RW, r = k - kh*RW;
  float v = 0.f;
  if (r < 5*CA) {
    int kw = r / CA, c = r % CA;
    if (o < O && c < I) v = w[((long)o*I + c)*25 + kh*5 + kw] * 32.0f;
  }
  Bt[e] = f2fp8(v);
}

// zero-padded transform biases (vector-safe loads in epilogues)
__global__ void padbias_k(const float* __restrict__ etb, const float* __restrict__ dtb,
                          float* __restrict__ tbe, float* __restrict__ tbd)
{
  int i = threadIdx.x;   // 512
  if (i < 416) tbe[i] = (i < 394) ? etb[i] : 0.f;
  if (i < 352) tbd[i] = (i < 327) ? dtb[i] : 0.f;
}

// Wcomb[c][pix*3+o] = sum_m write_w[c,m,ki,kj] * obs_w[o,m]   (pix = ki*4+kj)
__global__ void wcomb_k(const float* __restrict__ ww, const float* __restrict__ ow,
                        float* __restrict__ Wc)
{
  int idx = blockIdx.x*256 + threadIdx.x;
  if (idx >= 128*48) return;
  int c = idx / 48, rst = idx % 48;
  int pix = rst / 3, o = rst % 3;
  int ki = pix >> 2, kj = pix & 3;
  float a = 0.f;
  for (int mm=0; mm<128; mm++)
    a += ww[(((long)c*128 + mm)*4 + ki)*4 + kj] * ow[o*128 + mm];
  Wc[idx] = a;
}

// xr = conv(x, read_w, stride 4), xr[m*3+o]
__global__ void xr_k(const float* __restrict__ x, const float* __restrict__ rw,
                     float* __restrict__ xr)
{
  int idx = blockIdx.x*256 + threadIdx.x;
  if (idx >= MTOT*3) return;
  int m = idx / 3, o = idx % 3;
  int nb = m>>8, iy=(m>>4)&15, ix=m&15;
  float a = 0.f;
  for (int c=0;c<3;c++)
    for (int kh=0;kh<4;kh++)
      for (int kw=0;kw<4;kw++)
        a += x[((long)(nb*3+c)*64 + (iy*4+kh))*64 + (ix*4+kw)] * rw[((o*3+c)*4+kh)*4+kw];
  xr[idx] = a;
}

// static concat part for enc: channels 128..393 of ST_enc (stride 416)
__global__ void st_enc_k(const float* __restrict__ xr, const float* __restrict__ v,
                         const float* __restrict__ r, bf16* __restrict__ ST)
{
  long g = (long)blockIdx.x*256 + threadIdx.x;
  if (g >= (long)MTOT*266) return;
  int m = (int)(g / 266), ch = (int)(g % 266);
  int nb = m>>8, sp = m&255;
  float val;
  if (ch < 3)       val = xr[m*3 + ch];
  else if (ch < 10) val = v[nb*7 + ch - 3];
  else              val = r[((long)nb*256 + (ch-10))*256 + sp];
  ST[(long)m*416 + 128 + ch] = __float2bfloat16(val);
}

// static concat part for dec: channels 64..326 of ST_dec (stride 352)
__global__ void st_dec_k(const float* __restrict__ v, const float* __restrict__ r,
                         bf16* __restrict__ ST)
{
  long g = (long)blockIdx.x*256 + threadIdx.x;
  if (g >= (long)MTOT*263) return;
  int m = (int)(g / 263), ch = (int)(g % 263);
  int nb = m>>8, sp = m&255;
  float val;
  if (ch < 7) val = v[nb*7 + ch];
  else        val = r[((long)nb*256 + (ch-7))*256 + sp];
  ST[(long)m*352 + 64 + ch] = __float2bfloat16(val);
}

// LSTM core: 8 channels per thread, vectorized loads/stores.
// SB: also store bf16 h (needed for dec; enc's bf16 h has no consumers).
template<bool SB>
DEVI void lstm8_(const bf16* __restrict__ gates, float* __restrict__ cbuf,
                 bf16* __restrict__ hpad, unsigned char* __restrict__ h8,
                 int m, int c0, float* hout)
{
  long gb = ((long)m<<9) + c0;
  short8 gf = *(const short8*)(gates + gb);
  short8 gi = *(const short8*)(gates + gb + 128);
  short8 go = *(const short8*)(gates + gb + 256);
  short8 gs = *(const short8*)(gates + gb + 384);
  float* cb = cbuf + ((long)m<<7) + c0;
  f32x4 cv0 = *(f32x4*)cb;
  f32x4 cv1 = *(f32x4*)(cb+4);
  short8 hh;
  #pragma unroll
  for (int j=0;j<8;j++){
    float f = s2f(gf[j]);
    float i = s2f(gi[j]);
    float o = s2f(go[j]);
    float s = s2f(gs[j]);
    float cell = sigm_(f)*((j<4)?cv0[j]:cv1[j-4]) + sigm_(i)*tanhf(s);
    if (j<4) cv0[j]=cell; else cv1[j-4]=cell;
    float h = sigm_(o)*tanhf(cell);
    hout[j] = h;
    if constexpr (SB) hh[j] = f2s(h);
  }
  *(f32x4*)cb = cv0;
  *(f32x4*)(cb+4) = cv1;
  long hp = (pidx_(m)<<7) + c0;
  if constexpr (SB) *(short8*)(hpad + hp) = hh;
  int w0 = __builtin_amdgcn_cvt_pk_fp8_f32(hout[0], hout[1], 0, false);
  w0 = __builtin_amdgcn_cvt_pk_fp8_f32(hout[2], hout[3], w0, true);
  int w1 = __builtin_amdgcn_cvt_pk_fp8_f32(hout[4], hout[5], 0, false);
  w1 = __builtin_amdgcn_cvt_pk_fp8_f32(hout[6], hout[7], w1, true);
  i32x2 pw; pw[0]=w0; pw[1]=w1;
  *(i32x2*)(h8 + hp) = pw;
}

// enc LSTM: grid 1024 x 256 threads, 16 m x 128 c per block (fp8 h only).
__global__ __launch_bounds__(256)
void lstm_k(const bf16* __restrict__ gates, float* __restrict__ cbuf,
            unsigned char* __restrict__ h8)
{
  const int tid = threadIdx.x;
  const int m = (blockIdx.x<<4) + (tid>>4);
  const int c0 = (tid&15)<<3;
  float h[8];
  lstm8_<false>(gates, cbuf, nullptr, h8, m, c0, h);
}

// dec LSTM + fused wrc canvas accumulate (covers h^1..h^8 over the loop).
__global__ __launch_bounds__(256)
void lstm_wrc_k(const bf16* __restrict__ gates, float* __restrict__ cbuf,
                bf16* __restrict__ hpad, unsigned char* __restrict__ h8,
                const float* __restrict__ Wc, float* __restrict__ uc)
{
  __shared__ float Wl[6144];
  __shared__ float hl[16*128];
  const int tid = threadIdx.x;
  for (int i = tid; i < 6144; i += 256) Wl[i] = Wc[i];
  const int mloc = tid>>4;
  const int m = (blockIdx.x<<4) + mloc;
  const int c0 = (tid&15)<<3;
  float h[8];
  lstm8_<true>(gates, cbuf, hpad, h8, m, c0, h);
  #pragma unroll
  for (int j=0;j<8;j++) hl[(mloc<<7) + c0 + j] = h[j];
  __syncthreads();

  const int pix = tid&15;
  const float* hrow = hl + (mloc<<7);
  float a0=0.f, a1=0.f, a2=0.f;
  #pragma unroll 4
  for (int c=0;c<128;c++) {
    float hv = hrow[c];
    const float* wl = Wl + c*48 + pix*3;
    a0 += hv*wl[0]; a1 += hv*wl[1]; a2 += hv*wl[2];
  }
  const int nb = m>>8, iy=(m>>4)&15, ix=m&15;
  const int ki = pix>>2, kj = pix&3;
  long ob = ((long)((nb<<6) + (iy<<2) + ki)*64 + (ix<<2) + kj)*3;
  uc[ob+0] += a0; uc[ob+1] += a1; uc[ob+2] += a2;
}

// z = q_mu + exp(0.5 q_lv)*eps (q = 4 post partials + bias); ADD z into
// fp8 sDec ch 0..63 ; KL partial per block.
__global__ void zkl4_k(const bf16* __restrict__ PP, const float* __restrict__ pb,
                       const float* __restrict__ prior, const float* __restrict__ eps_t,
                       unsigned char* __restrict__ sDec8, float* __restrict__ part)
{
  __shared__ float wsum[4];
  const long PL = (long)MTOT*128;
  int idx = blockIdx.x*256 + threadIdx.x;   // exactly MTOT*64
  int m = idx >> 6, c = idx & 63;
  float qm = pb[c], ql = pb[64 + c];
  #pragma unroll
  for (int z=0; z<4; ++z) {
    qm += __bfloat162float(PP[z*PL + ((long)m<<7) + c]);
    ql += __bfloat162float(PP[z*PL + ((long)m<<7) + 64 + c]);
  }
  long pbx = (long)m << 7;
  float pm = prior[pbx + c], pl = prior[pbx + 64 + c];
  int nb = m>>8, sp = m&255;
  float e = eps_t[((long)nb*64 + c)*256 + sp];
  float z = qm + expf(0.5f*ql)*e;
  long so = pidx_(m)*352 + c;
  sDec8[so] = f2fp8(fp82f(sDec8[so]) + z);
  float kl = expf(ql - pl) + (pm-qm)*(pm-qm)*expf(-pl) - 1.f + (pl - ql);
  #pragma unroll
  for (int off=32; off>0; off>>=1) kl += __shfl_down(kl, off);
  if ((threadIdx.x & 63) == 0) wsum[threadIdx.x >> 6] = kl;
  __syncthreads();
  if (threadIdx.x == 0)
    part[blockIdx.x] = wsum[0] + wsum[1] + wsum[2] + wsum[3];
}

__global__ void canvas_k(const float* __restrict__ uc, const float* __restrict__ ob,
                         float* __restrict__ out)
{
  int idx = blockIdx.x*256 + threadIdx.x;   // exactly 786432, NCHW order
  int x = idx & 63, y = (idx>>6)&63;
  int rem = idx >> 12;
  int o = rem % 3, n = rem / 3;
  float v = uc[((long)((n<<6)+y)*64 + x)*3 + o] + ob[o];
  out[idx] = 1.f/(1.f+expf(-v));
}

// final KL: sum 8*4096 per-block partials, scale, write out[786432]
__global__ void klred_k(const float* __restrict__ part, float* __restrict__ out)
{
  __shared__ float wsum[4];
  float a = 0.f;
  for (int i = threadIdx.x; i < 32768; i += 256) a += part[i];
  #pragma unroll
  for (int off=32; off>0; off>>=1) a += __shfl_down(a, off);
  if ((threadIdx.x & 63) == 0) wsum[threadIdx.x >> 6] = a;
  __syncthreads();
  if (threadIdx.x == 0)
    out[786432] = (wsum[0] + wsum[1] + wsum[2] + wsum[3]) * (0.5f/64.f);
}

// ---------------------------------------------------------------------------
// workspace layout (bytes). fp8 tenants reuse oversized bf16-era slots.
// encG Kp8 = 5*17*128 = 10880 (512*10880 = 5.57MB <= 10.65MB slot);
// decG Kp8 = 5*14*128 = 8960 (4.59MB <= 9.01MB slot). CA=128 rows exact.
static const long O_BT_POST  = 0;                     // fp8 128*3200
static const long O_BT_ENCT  = O_BT_POST  + 819200;   // fp8 512*3200
static const long O_BT_DP    = O_BT_ENCT  + 3276800;  // fp8 512*3200
static const long O_BT_ENCG  = O_BT_DP    + 3276800;  // fp8 512*10880
static const long O_BT_DECG  = O_BT_ENCG  + 10649600; // fp8 512*8960
static const long O_WCOMB    = O_BT_DECG  + 9011200;  // 6144*4
static const long O_XR       = O_WCOMB    + 24576;    // 49152*4
static const long O_KLP      = O_XR       + 196608;   // 32768*4
static const long O_STENC    = O_KLP      + 131072;   // 16384*416*2
static const long O_STDEC    = O_STENC    + 13631488; // 16384*352*2
static const long O_HENC     = O_STDEC    + 11534336; // (unused bf16 slot)
static const long O_HDEC     = O_HENC     + 6553600;
static const long O_SENC     = O_HDEC     + 6553600;  // fp8 25600*416 (+overread pad)
static const long O_SDEC     = O_SENC     + 21299200; // fp8 25600*352 (+overread pad)
static const long O_CENC     = O_SDEC     + 18022400; // 16384*128*4
static const long O_CDEC     = O_CENC     + 8388608;
static const long O_PRIOR    = O_CDEC     + 8388608;  // 16384*128*4
static const long O_H8E      = O_PRIOR    + 8388608;  // fp8 25600*128
static const long O_H8D      = O_H8E      + 3276800;
static const long O_PG       = O_H8D      + 3276800;  // Gates 16.7MB + PostP 16.7MB
static const long O_UC       = O_PG       + 33554432; // 786432*4
static const long O_TBE      = O_UC       + 3145728;  // padded enc_tb (416*4)
static const long O_TBD      = O_TBE      + 2048;     // padded dec_tb (352*4)
static const long WS_TOTAL   = O_TBD      + 2048;

extern "C" void kernel_launch(void* const* d_in, const int* in_sizes, int n_in,
                              void* d_out, int out_size, void* d_ws, size_t ws_size,
                              hipStream_t stream)
{
  const float* x       = (const float*)d_in[0];
  const float* v       = (const float*)d_in[1];
  const float* r       = (const float*)d_in[2];
  const float* eps     = (const float*)d_in[3];
  const float* read_w  = (const float*)d_in[4];
  const float* write_w = (const float*)d_in[5];
  const float* prior_w = (const float*)d_in[6];
  const float* prior_b = (const float*)d_in[7];
  const float* post_w  = (const float*)d_in[8];
  const float* post_b  = (const float*)d_in[9];
  const float* enc_gw  = (const float*)d_in[10];
  const float* enc_gb  = (const float*)d_in[11];
  const float* enc_tw  = (const float*)d_in[12];
  const float* enc_tb  = (const float*)d_in[13];
  const float* dec_gw  = (const float*)d_in[14];
  const float* dec_gb  = (const float*)d_in[15];
  const float* dec_tw  = (const float*)d_in[16];
  const float* dec_tb  = (const float*)d_in[17];
  const float* obs_w   = (const float*)d_in[18];
  const float* obs_b   = (const float*)d_in[19];

  char* ws = (char*)d_ws;
  unsigned char* Bt8Post = (unsigned char*)(ws + O_BT_POST);
  unsigned char* Bt8EncT = (unsigned char*)(ws + O_BT_ENCT);
  unsigned char* Bt8DP   = (unsigned char*)(ws + O_BT_DP);
  unsigned char* Bt8EncG = (unsigned char*)(ws + O_BT_ENCG);
  unsigned char* Bt8DecG = (unsigned char*)(ws + O_BT_DECG);
  float* Wcomb  = (float*)(ws + O_WCOMB);
  float* XR     = (float*)(ws + O_XR);
  float* KLpart = (float*)(ws + O_KLP);
  bf16* STenc   = (bf16*)(ws + O_STENC);
  bf16* STdec   = (bf16*)(ws + O_STDEC);
  bf16* hDec    = (bf16*)(ws + O_HDEC);
  unsigned char* sEnc8 = (unsigned char*)(ws + O_SENC);
  unsigned char* sDec8 = (unsigned char*)(ws + O_SDEC);
  float* cEnc   = (float*)(ws + O_CENC);
  float* cDec   = (float*)(ws + O_CDEC);
  float* PriorO = (float*)(ws + O_PRIOR);
  unsigned char* h8Enc = (unsigned char*)(ws + O_H8E);
  unsigned char* h8Dec = (unsigned char*)(ws + O_H8D);
  bf16* Gates   = (bf16*)(ws + O_PG);
  bf16* PostP   = (bf16*)(ws + O_PG + 16777216);
  float* Ucomb  = (float*)(ws + O_UC);
  float* TBE    = (float*)(ws + O_TBE);
  float* TBD    = (float*)(ws + O_TBD);
  float* out    = (float*)d_out;

  size_t clr = (size_t)WS_TOTAL; if (clr > ws_size) clr = ws_size;
  hipMemsetAsync(d_ws, 0, clr, stream);

  // weight repacks (all fp8, kh-row-grouped) + padded biases
  repack_w8_k<<<1600, 256, 0, stream>>>(post_w, Bt8Post, 128, 128, 128, 5, 128L*3200);
  repack_w8_k<<<6400, 256, 0, stream>>>(enc_tw, Bt8EncT, 394, 128, 128, 5, 512L*3200);
  repack_w8_k<<<4800, 256, 0, stream>>>(dec_tw, Bt8DP, 327, 128, 128, 5, 384L*3200);
  repack_w8_k<<<1600, 256, 0, stream>>>(prior_w, Bt8DP + 384L*3200, 128, 128, 128, 5, 128L*3200);
  repack_w8_k<<<21760, 256, 0, stream>>>(enc_gw, Bt8EncG, 512, 394, 416, 17, 512L*10880);
  repack_w8_k<<<17920, 256, 0, stream>>>(dec_gw, Bt8DecG, 512, 327, 352, 14, 512L*8960);
  padbias_k<<<1, 512, 0, stream>>>(enc_tb, dec_tb, TBE, TBD);
  wcomb_k<<<24, 256, 0, stream>>>(write_w, obs_w, Wcomb);
  xr_k<<<192, 256, 0, stream>>>(x, read_w, XR);
  st_enc_k<<<(int)(((long)MTOT*266 + 255)/256), 256, 0, stream>>>(XR, v, r, STenc);
  st_dec_k<<<(int)(((long)MTOT*263 + 255)/256), 256, 0, stream>>>(v, r, STdec);

  for (int t = 0; t < 8; ++t) {
    // merged fp8 T-convs (decT+prior | encT), vectorized C^T epilogues
    conv_tp8<<<dim3(128,4,2), 256, 0, stream>>>(
        h8Dec, h8Enc, Bt8DP, Bt8EncT, TBD, prior_b, TBE,
        PriorO, sDec8, STdec, sEnc8, STenc, hDec);
    // enc gates: MX-fp8, conflict-free frag-order LDS
    conv_g8<416,17><<<dim3(128,4), 256, 0, stream>>>(sEnc8, Bt8EncG, enc_gb, Gates);
    lstm_k<<<1024, 256, 0, stream>>>(Gates, cEnc, h8Enc);
    // post: MX-fp8 split-K=4 -> bf16 partial planes
    conv_p8<<<dim3(128,1,4), 256, 0, stream>>>(h8Enc, Bt8Post, PostP);
    // z (sum partials + bias) -> add into fp8 sDec ch0..63 ; KL partials
    zkl4_k<<<4096, 256, 0, stream>>>(PostP, post_b, PriorO,
                                     eps + (long)t*64*64*256, sDec8,
                                     KLpart + (long)t*4096);
    // dec gates: MX-fp8
    conv_g8<352,14><<<dim3(128,4), 256, 0, stream>>>(sDec8, Bt8DecG, dec_gb, Gates);
    // dec LSTM + fused canvas accumulate (covers h^1..h^8 over the loop)
    lstm_wrc_k<<<1024, 256, 0, stream>>>(Gates, cDec, hDec, h8Dec, Wcomb, Ucomb);
  }

  canvas_k<<<3072, 256, 0, stream>>>(Ucomb, obs_b, out);
  klred_k<<<1, 256, 0, stream>>>(KLpart, out);
}

// Round 20
// 2467.428 us; speedup vs baseline: 1.3598x; 1.3598x over previous
//
#include <hip/hip_runtime.h>
#include <hip/hip_bf16.h>

using bf16 = __hip_bfloat16;
typedef __attribute__((ext_vector_type(8))) short short8;
typedef __attribute__((ext_vector_type(4))) short s16x4;
typedef __attribute__((ext_vector_type(4))) float f32x4;
typedef __attribute__((ext_vector_type(8))) int i32x8;
typedef __attribute__((ext_vector_type(4))) int i32x4;
typedef __attribute__((ext_vector_type(2))) int i32x2;

#define DEVI __device__ __forceinline__

#define MTOT 16384      // 64 * 16 * 16 output positions
#define PADS 25600      // 64 * 20 * 20 padded positions

DEVI float sigm_(float x){ return 1.f/(1.f+expf(-x)); }

// bf16 (raw short) -> f32: exact 16-bit shift.
DEVI float s2f(short v){
  unsigned u = ((unsigned)(unsigned short)v) << 16;
  return __builtin_bit_cast(float, u);
}
DEVI short f2s(float x){
  bf16 hb = __float2bfloat16(x);
  return __builtin_bit_cast(short, hb);
}

DEVI long pidx_(int m){
  int nb = m>>8, iy=(m>>4)&15, ix=m&15;
  return (long)(nb*20 + iy + 2)*20 + (ix + 2);
}

DEVI unsigned char f2fp8(float x){
  int p = __builtin_amdgcn_cvt_pk_fp8_f32(x, 0.f, 0, false);
  return (unsigned char)(p & 0xFF);
}
DEVI float fp82f(unsigned char v){
  return __builtin_amdgcn_cvt_f32_fp8((int)v, 0);
}
DEVI unsigned pack4fp8(float a, float b, float c, float d){
  int w = __builtin_amdgcn_cvt_pk_fp8_f32(a, b, 0, false);
  w     = __builtin_amdgcn_cvt_pk_fp8_f32(c, d, w, true);
  return (unsigned)w;
}

// async global->LDS, 16B per lane. LDS dest = wave-uniform base + lane*16.
DEVI void async16(const void* g, void* l) {
  __builtin_amdgcn_global_load_lds(
      (__attribute__((address_space(1))) void*)(unsigned long long)g,
      (__attribute__((address_space(3))) void*)(unsigned int)(unsigned long long)l,
      16, 0, 0);
}

// ---------------------------------------------------------------------------
// MX-fp8 GEMM core v3 = r18 layout + row-grouped K. BM=128, BN=128, BK=128,
// 4 waves 2Mx2N, double-buffered 64KB LDS -> 2 blocks/CU, TRANSPOSED output
// (operand swap, C^T frag layout: lane holds 4 consecutive n at fixed m).
//
// K layout: grouped per kh-row, row padded to NROW*128 (Kp8 = 5*NROW*128).
// B zero-padded in the pad; A over-reads valid memory x zero weights. No
// subtile crosses a kh row (straddle fixed); staging shift advances by a
// CONSTANT +128/subtile with one scalar bump per row (no div/mod).
//
// Staging (r18, COALESCED): piece p -> row p>>3, phys chunk p&7 holding
// logical chunk (p&7)^(row&7); per 8-lane group the global reads cover one
// contiguous 128B row segment. Per-lane chunk offset lc*16 folded into base.
// LDS reads use the same XOR (c0/c1), ~2-way aliasing.
// scale_a=122 (weights x2^5 undone exactly), scale_b=127.
// Runtime subtile range [ns0, ns0+nst) for split-K.
// ---------------------------------------------------------------------------
template<int CA, int NROW>
DEVI void g8_core(const unsigned char* __restrict__ A8,
                  const unsigned char* __restrict__ Bt8,
                  int m0, int n0, unsigned char* AsB, unsigned char* BsB,
                  f32x4 (&acc)[4][4], int ns0, int nst)
{
  constexpr int Kp8 = 5*NROW*128;
  const int tid = threadIdx.x;
  const int wv = tid>>6, ln = tid&63;

  const int rr = tid>>3;                 // piece row (0..31; +32 per i)
  const int lc = (tid&7) ^ (rr&7);       // logical chunk this lane stages
  long paA[4], pbB[4];
  #pragma unroll
  for (int i=0;i<4;i++){
    const int mA = m0 + rr + (i<<5);
    paA[i] = (long)(((mA>>8)*20 + ((mA>>4)&15))*20 + (mA&15))*CA + lc*16;
    pbB[i] = (long)(n0 + rr + (i<<5))*Kp8 + lc*16;
  }

  int rowc = ns0 % NROW;
  long sh = (long)(ns0/NROW)*20*CA + (long)rowc*128;
  long ks = (long)ns0*128;

  auto stage = [&](int d){
    char* la = (char*)AsB + d*16384 + (wv<<10);
    char* lb = (char*)BsB + d*16384 + (wv<<10);
    #pragma unroll
    for (int i=0;i<4;i++) async16(A8 + paA[i] + sh, la + i*4096);
    #pragma unroll
    for (int i=0;i<4;i++) async16(Bt8 + pbB[i] + ks, lb + i*4096);
    ks += 128; sh += 128;
    if (++rowc == NROW){ rowc = 0; sh += 20*CA - (long)NROW*128; }
  };

  const int wm = wv>>1, wn = wv&1;
  const int rA0 = (wm<<6) + (ln&15);
  const int rB0 = (wn<<6) + (ln&15);
  const int xa = ln&7;
  const int q2 = (ln>>4)<<1;
  const int c0 = ((q2    ) ^ xa)<<4;
  const int c1 = ((q2 | 1) ^ xa)<<4;

  stage(0);
  for (int t=0; t<nst; ++t) {
    asm volatile("s_waitcnt vmcnt(0)\ns_barrier" ::: "memory");
    if (t+1 < nst) stage((t+1)&1);

    const char* as_ = (const char*)AsB + (t&1)*16384;
    const char* bs_ = (const char*)BsB + (t&1)*16384;
    i32x8 af[4], bfr[4];
    #pragma unroll
    for (int f=0; f<4; f++){
      const char* p = as_ + ((rA0 + (f<<4))<<7);
      ((i32x4*)&af[f])[0] = *(const i32x4*)(p + c0);
      ((i32x4*)&af[f])[1] = *(const i32x4*)(p + c1);
    }
    #pragma unroll
    for (int f=0; f<4; f++){
      const char* p = bs_ + ((rB0 + (f<<4))<<7);
      ((i32x4*)&bfr[f])[0] = *(const i32x4*)(p + c0);
      ((i32x4*)&bfr[f])[1] = *(const i32x4*)(p + c1);
    }
    __builtin_amdgcn_s_setprio(1);
    #pragma unroll
    for (int bf=0; bf<4; bf++)
      #pragma unroll
      for (int afi=0; afi<4; afi++)
        acc[bf][afi] = __builtin_amdgcn_mfma_scale_f32_16x16x128_f8f6f4(
            bfr[bf], af[afi], acc[bf][afi], 0, 0, 0, 122, 0, 127);
    __builtin_amdgcn_s_setprio(0);
  }
}

// gates GEMM: bf16 out stride 512 + bias; vectorized (C^T) epilogue.
template<int CA, int NROW>
__global__ __launch_bounds__(256)
void conv_g8(const unsigned char* __restrict__ A8,
             const unsigned char* __restrict__ Bt8,
             const float* __restrict__ bias, bf16* __restrict__ outB)
{
  __shared__ alignas(16) unsigned char As[2][16384];
  __shared__ alignas(16) unsigned char Bs[2][16384];
  const int m0 = blockIdx.x<<7, n0 = blockIdx.y<<7;
  f32x4 acc[4][4] = {};
  g8_core<CA,NROW>(A8, Bt8, m0, n0, &As[0][0], &Bs[0][0], acc, 0, 5*NROW);

  const int tid = threadIdx.x;
  const int wv = tid>>6, ln = tid&63;
  const int mb = m0 + ((wv>>1)<<6);
  const int nb = n0 + ((wv&1)<<6);
  const int ml = (ln>>4)<<2;
  const int nl = ln&15;
  #pragma unroll
  for (int bf=0; bf<4; bf++)
    #pragma unroll
    for (int afi=0; afi<4; afi++) {
      const long m = mb + (afi<<4) + nl;
      const int n = nb + (bf<<4) + ml;
      f32x4 b = *(const f32x4*)(bias + n);
      f32x4 v = acc[bf][afi];
      s16x4 o;
      #pragma unroll
      for (int j=0;j<4;j++) o[j] = f2s(v[j] + b[j]);
      *(s16x4*)(outB + (m<<9) + n) = o;
    }
}

// merged fp8 T-convs, vectorized (C^T) epilogues:
// z=0 decT+prior: n<352 -> sDec8 (+TBD+ST) ; n0==384 -> PriorO f32 (+pb)
// z=1 encT:       n<416 -> sEnc8 (+TBE+ST+hDec(n<128))
__global__ __launch_bounds__(256)
void conv_tp8(const unsigned char* __restrict__ h8Dec,
              const unsigned char* __restrict__ h8Enc,
              const unsigned char* __restrict__ Bt8DP,
              const unsigned char* __restrict__ Bt8EncT,
              const float* __restrict__ TBD, const float* __restrict__ prior_b,
              const float* __restrict__ TBE,
              float* __restrict__ PriorO,
              unsigned char* __restrict__ sDec8, const bf16* __restrict__ STdec,
              unsigned char* __restrict__ sEnc8, const bf16* __restrict__ STenc,
              const bf16* __restrict__ hDecB)
{
  __shared__ alignas(16) unsigned char As[2][16384];
  __shared__ alignas(16) unsigned char Bs[2][16384];
  const int z = blockIdx.z;
  const int m0 = blockIdx.x<<7, n0 = blockIdx.y<<7;
  f32x4 acc[4][4] = {};
  if (z == 0) g8_core<128,5>(h8Dec, Bt8DP,   m0, n0, &As[0][0], &Bs[0][0], acc, 0, 25);
  else        g8_core<128,5>(h8Enc, Bt8EncT, m0, n0, &As[0][0], &Bs[0][0], acc, 0, 25);

  const int tid = threadIdx.x;
  const int wv = tid>>6, ln = tid&63;
  const int mb = m0 + ((wv>>1)<<6);
  const int nb = n0 + ((wv&1)<<6);
  const int ml = (ln>>4)<<2;
  const int nl = ln&15;
  #pragma unroll
  for (int afi=0; afi<4; afi++) {
    const long m = mb + (afi<<4) + nl;
    const long pI = pidx_(m);
    #pragma unroll
    for (int bf=0; bf<4; bf++) {
      const int n = nb + (bf<<4) + ml;
      f32x4 v = acc[bf][afi];
      if (z == 0) {
        if (n0 == 384) {            // prior: f32 [m][128] + prior_b
          f32x4 b = *(const f32x4*)(prior_b + (n-384));
          *(f32x4*)(PriorO + (m<<7) + (n-384)) = v + b;
        } else if (n < 352) {       // sDec8 fp8, +tb +ST
          f32x4 tb = *(const f32x4*)(TBD + n);
          s16x4 st = *(const s16x4*)(STdec + m*352 + n);
          float f0 = v[0]+tb[0]+s2f(st[0]);
          float f1 = v[1]+tb[1]+s2f(st[1]);
          float f2 = v[2]+tb[2]+s2f(st[2]);
          float f3 = v[3]+tb[3]+s2f(st[3]);
          *(unsigned*)(sDec8 + pI*352 + n) = pack4fp8(f0,f1,f2,f3);
        }
      } else {
        if (n < 416) {              // sEnc8 fp8, +tb +ST (+hDec if n<128)
          f32x4 tb = *(const f32x4*)(TBE + n);
          s16x4 st = *(const s16x4*)(STenc + m*416 + n);
          float f0 = v[0]+tb[0]+s2f(st[0]);
          float f1 = v[1]+tb[1]+s2f(st[1]);
          float f2 = v[2]+tb[2]+s2f(st[2]);
          float f3 = v[3]+tb[3]+s2f(st[3]);
          if (n < 128) {
            s16x4 e = *(const s16x4*)(hDecB + (pI<<7) + n);
            f0 += s2f(e[0]); f1 += s2f(e[1]); f2 += s2f(e[2]); f3 += s2f(e[3]);
          }
          *(unsigned*)(sEnc8 + pI*416 + n) = pack4fp8(f0,f1,f2,f3);
        }
      }
    }
  }
}

// post GEMM: MX-fp8 split-K=4, bf16 partial planes [z][m][128], C^T epilogue.
__global__ __launch_bounds__(256)
void conv_p8(const unsigned char* __restrict__ h8Enc,
             const unsigned char* __restrict__ Bt8Post,
             bf16* __restrict__ PP)
{
  __shared__ alignas(16) unsigned char As[2][16384];
  __shared__ alignas(16) unsigned char Bs[2][16384];
  const int z = blockIdx.z;
  const int s0[4]  = {0, 7, 13, 19};
  const int len[4] = {7, 6, 6, 6};
  const int m0 = blockIdx.x<<7;
  f32x4 acc[4][4] = {};
  g8_core<128,5>(h8Enc, Bt8Post, m0, 0, &As[0][0], &Bs[0][0], acc, s0[z], len[z]);

  bf16* plane = PP + (long)z*MTOT*128;
  const int tid = threadIdx.x;
  const int wv = tid>>6, ln = tid&63;
  const int mb = m0 + ((wv>>1)<<6);
  const int nb = (wv&1)<<6;
  const int ml = (ln>>4)<<2;
  const int nl = ln&15;
  #pragma unroll
  for (int bf=0; bf<4; bf++)
    #pragma unroll
    for (int afi=0; afi<4; afi++) {
      const long m = mb + (afi<<4) + nl;
      const int n = nb + (bf<<4) + ml;
      f32x4 v = acc[bf][afi];
      s16x4 o;
      #pragma unroll
      for (int j=0;j<4;j++) o[j] = f2s(v[j]);
      *(s16x4*)(plane + (m<<7) + n) = o;
    }
}

// fp8 repack, kh-row-grouped K with row padded to NROW*128 (zeros in pad),
// weights x32 (undone by MFMA scale 2^-5).
__global__ void repack_w8_k(const float* __restrict__ w, unsigned char* __restrict__ Bt,
                            int O, int I, int CA, int NROW, long total)
{
  long e = (long)blockIdx.x*256 + threadIdx.x;
  if (e >= total) return;
  const int RW = NROW*128;
  const int Kp8 = 5*RW;
  int o = (int)(e / Kp8);
  int k = (int)(e % Kp8);
  int kh = k / RW, r = k - kh*RW;
  float v = 0.f;
  if (r < 5*CA) {
    int kw = r / CA, c = r % CA;
    if (o < O && c < I) v = w[((long)o*I + c)*25 + kh*5 + kw] * 32.0f;
  }
  Bt[e] = f2fp8(v);
}

// zero-padded transform biases (vector-safe loads in epilogues)
__global__ void padbias_k(const float* __restrict__ etb, const float* __restrict__ dtb,
                          float* __restrict__ tbe, float* __restrict__ tbd)
{
  int i = threadIdx.x;   // 512
  if (i < 416) tbe[i] = (i < 394) ? etb[i] : 0.f;
  if (i < 352) tbd[i] = (i < 327) ? dtb[i] : 0.f;
}

// Wcomb[c][pix*3+o] = sum_m write_w[c,m,ki,kj] * obs_w[o,m]   (pix = ki*4+kj)
__global__ void wcomb_k(const float* __restrict__ ww, const float* __restrict__ ow,
                        float* __restrict__ Wc)
{
  int idx = blockIdx.x*256 + threadIdx.x;
  if (idx >= 128*48) return;
  int c = idx / 48, rst = idx % 48;
  int pix = rst / 3, o = rst % 3;
  int ki = pix >> 2, kj = pix & 3;
  float a = 0.f;
  for (int mm=0; mm<128; mm++)
    a += ww[(((long)c*128 + mm)*4 + ki)*4 + kj] * ow[o*128 + mm];
  Wc[idx] = a;
}

// xr = conv(x, read_w, stride 4), xr[m*3+o]
__global__ void xr_k(const float* __restrict__ x, const float* __restrict__ rw,
                     float* __restrict__ xr)
{
  int idx = blockIdx.x*256 + threadIdx.x;
  if (idx >= MTOT*3) return;
  int m = idx / 3, o = idx % 3;
  int nb = m>>8, iy=(m>>4)&15, ix=m&15;
  float a = 0.f;
  for (int c=0;c<3;c++)
    for (int kh=0;kh<4;kh++)
      for (int kw=0;kw<4;kw++)
        a += x[((long)(nb*3+c)*64 + (iy*4+kh))*64 + (ix*4+kw)] * rw[((o*3+c)*4+kh)*4+kw];
  xr[idx] = a;
}

// static concat part for enc: channels 128..393 of ST_enc (stride 416)
__global__ void st_enc_k(const float* __restrict__ xr, const float* __restrict__ v,
                         const float* __restrict__ r, bf16* __restrict__ ST)
{
  long g = (long)blockIdx.x*256 + threadIdx.x;
  if (g >= (long)MTOT*266) return;
  int m = (int)(g / 266), ch = (int)(g % 266);
  int nb = m>>8, sp = m&255;
  float val;
  if (ch < 3)       val = xr[m*3 + ch];
  else if (ch < 10) val = v[nb*7 + ch - 3];
  else              val = r[((long)nb*256 + (ch-10))*256 + sp];
  ST[(long)m*416 + 128 + ch] = __float2bfloat16(val);
}

// static concat part for dec: channels 64..326 of ST_dec (stride 352)
__global__ void st_dec_k(const float* __restrict__ v, const float* __restrict__ r,
                         bf16* __restrict__ ST)
{
  long g = (long)blockIdx.x*256 + threadIdx.x;
  if (g >= (long)MTOT*263) return;
  int m = (int)(g / 263), ch = (int)(g % 263);
  int nb = m>>8, sp = m&255;
  float val;
  if (ch < 7) val = v[nb*7 + ch];
  else        val = r[((long)nb*256 + (ch-7))*256 + sp];
  ST[(long)m*352 + 64 + ch] = __float2bfloat16(val);
}

// LSTM core: 8 channels per thread, vectorized loads/stores.
// SB: also store bf16 h (needed for dec; enc's bf16 h has no consumers).
template<bool SB>
DEVI void lstm8_(const bf16* __restrict__ gates, float* __restrict__ cbuf,
                 bf16* __restrict__ hpad, unsigned char* __restrict__ h8,
                 int m, int c0, float* hout)
{
  long gb = ((long)m<<9) + c0;
  short8 gf = *(const short8*)(gates + gb);
  short8 gi = *(const short8*)(gates + gb + 128);
  short8 go = *(const short8*)(gates + gb + 256);
  short8 gs = *(const short8*)(gates + gb + 384);
  float* cb = cbuf + ((long)m<<7) + c0;
  f32x4 cv0 = *(f32x4*)cb;
  f32x4 cv1 = *(f32x4*)(cb+4);
  short8 hh;
  #pragma unroll
  for (int j=0;j<8;j++){
    float f = s2f(gf[j]);
    float i = s2f(gi[j]);
    float o = s2f(go[j]);
    float s = s2f(gs[j]);
    float cell = sigm_(f)*((j<4)?cv0[j]:cv1[j-4]) + sigm_(i)*tanhf(s);
    if (j<4) cv0[j]=cell; else cv1[j-4]=cell;
    float h = sigm_(o)*tanhf(cell);
    hout[j] = h;
    if constexpr (SB) hh[j] = f2s(h);
  }
  *(f32x4*)cb = cv0;
  *(f32x4*)(cb+4) = cv1;
  long hp = (pidx_(m)<<7) + c0;
  if constexpr (SB) *(short8*)(hpad + hp) = hh;
  int w0 = __builtin_amdgcn_cvt_pk_fp8_f32(hout[0], hout[1], 0, false);
  w0 = __builtin_amdgcn_cvt_pk_fp8_f32(hout[2], hout[3], w0, true);
  int w1 = __builtin_amdgcn_cvt_pk_fp8_f32(hout[4], hout[5], 0, false);
  w1 = __builtin_amdgcn_cvt_pk_fp8_f32(hout[6], hout[7], w1, true);
  i32x2 pw; pw[0]=w0; pw[1]=w1;
  *(i32x2*)(h8 + hp) = pw;
}

// enc LSTM: grid 1024 x 256 threads, 16 m x 128 c per block (fp8 h only).
__global__ __launch_bounds__(256)
void lstm_k(const bf16* __restrict__ gates, float* __restrict__ cbuf,
            unsigned char* __restrict__ h8)
{
  const int tid = threadIdx.x;
  const int m = (blockIdx.x<<4) + (tid>>4);
  const int c0 = (tid&15)<<3;
  float h[8];
  lstm8_<false>(gates, cbuf, nullptr, h8, m, c0, h);
}

// dec LSTM + fused wrc canvas accumulate (covers h^1..h^8 over the loop).
__global__ __launch_bounds__(256)
void lstm_wrc_k(const bf16* __restrict__ gates, float* __restrict__ cbuf,
                bf16* __restrict__ hpad, unsigned char* __restrict__ h8,
                const float* __restrict__ Wc, float* __restrict__ uc)
{
  __shared__ float Wl[6144];
  __shared__ float hl[16*128];
  const int tid = threadIdx.x;
  for (int i = tid; i < 6144; i += 256) Wl[i] = Wc[i];
  const int mloc = tid>>4;
  const int m = (blockIdx.x<<4) + mloc;
  const int c0 = (tid&15)<<3;
  float h[8];
  lstm8_<true>(gates, cbuf, hpad, h8, m, c0, h);
  #pragma unroll
  for (int j=0;j<8;j++) hl[(mloc<<7) + c0 + j] = h[j];
  __syncthreads();

  const int pix = tid&15;
  const float* hrow = hl + (mloc<<7);
  float a0=0.f, a1=0.f, a2=0.f;
  #pragma unroll 4
  for (int c=0;c<128;c++) {
    float hv = hrow[c];
    const float* wl = Wl + c*48 + pix*3;
    a0 += hv*wl[0]; a1 += hv*wl[1]; a2 += hv*wl[2];
  }
  const int nb = m>>8, iy=(m>>4)&15, ix=m&15;
  const int ki = pix>>2, kj = pix&3;
  long ob = ((long)((nb<<6) + (iy<<2) + ki)*64 + (ix<<2) + kj)*3;
  uc[ob+0] += a0; uc[ob+1] += a1; uc[ob+2] += a2;
}

// z = q_mu + exp(0.5 q_lv)*eps (q = 4 post partials + bias); ADD z into
// fp8 sDec ch 0..63 ; KL partial per block.
__global__ void zkl4_k(const bf16* __restrict__ PP, const float* __restrict__ pb,
                       const float* __restrict__ prior, const float* __restrict__ eps_t,
                       unsigned char* __restrict__ sDec8, float* __restrict__ part)
{
  __shared__ float wsum[4];
  const long PL = (long)MTOT*128;
  int idx = blockIdx.x*256 + threadIdx.x;   // exactly MTOT*64
  int m = idx >> 6, c = idx & 63;
  float qm = pb[c], ql = pb[64 + c];
  #pragma unroll
  for (int z=0; z<4; ++z) {
    qm += __bfloat162float(PP[z*PL + ((long)m<<7) + c]);
    ql += __bfloat162float(PP[z*PL + ((long)m<<7) + 64 + c]);
  }
  long pbx = (long)m << 7;
  float pm = prior[pbx + c], pl = prior[pbx + 64 + c];
  int nb = m>>8, sp = m&255;
  float e = eps_t[((long)nb*64 + c)*256 + sp];
  float z = qm + expf(0.5f*ql)*e;
  long so = pidx_(m)*352 + c;
  sDec8[so] = f2fp8(fp82f(sDec8[so]) + z);
  float kl = expf(ql - pl) + (pm-qm)*(pm-qm)*expf(-pl) - 1.f + (pl - ql);
  #pragma unroll
  for (int off=32; off>0; off>>=1) kl += __shfl_down(kl, off);
  if ((threadIdx.x & 63) == 0) wsum[threadIdx.x >> 6] = kl;
  __syncthreads();
  if (threadIdx.x == 0)
    part[blockIdx.x] = wsum[0] + wsum[1] + wsum[2] + wsum[3];
}

__global__ void canvas_k(const float* __restrict__ uc, const float* __restrict__ ob,
                         float* __restrict__ out)
{
  int idx = blockIdx.x*256 + threadIdx.x;   // exactly 786432, NCHW order
  int x = idx & 63, y = (idx>>6)&63;
  int rem = idx >> 12;
  int o = rem % 3, n = rem / 3;
  float v = uc[((long)((n<<6)+y)*64 + x)*3 + o] + ob[o];
  out[idx] = 1.f/(1.f+expf(-v));
}

// final KL: sum 8*4096 per-block partials, scale, write out[786432]
__global__ void klred_k(const float* __restrict__ part, float* __restrict__ out)
{
  __shared__ float wsum[4];
  float a = 0.f;
  for (int i = threadIdx.x; i < 32768; i += 256) a += part[i];
  #pragma unroll
  for (int off=32; off>0; off>>=1) a += __shfl_down(a, off);
  if ((threadIdx.x & 63) == 0) wsum[threadIdx.x >> 6] = a;
  __syncthreads();
  if (threadIdx.x == 0)
    out[786432] = (wsum[0] + wsum[1] + wsum[2] + wsum[3]) * (0.5f/64.f);
}

// ---------------------------------------------------------------------------
// workspace layout (bytes). fp8 tenants reuse oversized bf16-era slots.
// encG Kp8 = 5*17*128 = 10880 (5.57MB <= 10.65MB slot);
// decG Kp8 = 5*14*128 = 8960 (4.59MB <= 9.01MB slot). CA=128 rows exact.
static const long O_BT_POST  = 0;                     // fp8 128*3200
static const long O_BT_ENCT  = O_BT_POST  + 819200;   // fp8 512*3200
static const long O_BT_DP    = O_BT_ENCT  + 3276800;  // fp8 512*3200
static const long O_BT_ENCG  = O_BT_DP    + 3276800;  // fp8 512*10880
static const long O_BT_DECG  = O_BT_ENCG  + 10649600; // fp8 512*8960
static const long O_WCOMB    = O_BT_DECG  + 9011200;  // 6144*4
static const long O_XR       = O_WCOMB    + 24576;    // 49152*4
static const long O_KLP      = O_XR       + 196608;   // 32768*4
static const long O_STENC    = O_KLP      + 131072;   // 16384*416*2
static const long O_STDEC    = O_STENC    + 13631488; // 16384*352*2
static const long O_HENC     = O_STDEC    + 11534336; // (unused bf16 slot)
static const long O_HDEC     = O_HENC     + 6553600;
static const long O_SENC     = O_HDEC     + 6553600;  // fp8 25600*416 (+overread pad)
static const long O_SDEC     = O_SENC     + 21299200; // fp8 25600*352 (+overread pad)
static const long O_CENC     = O_SDEC     + 18022400; // 16384*128*4
static const long O_CDEC     = O_CENC     + 8388608;
static const long O_PRIOR    = O_CDEC     + 8388608;  // 16384*128*4
static const long O_H8E      = O_PRIOR    + 8388608;  // fp8 25600*128
static const long O_H8D      = O_H8E      + 3276800;
static const long O_PG       = O_H8D      + 3276800;  // Gates 16.7MB + PostP 16.7MB
static const long O_UC       = O_PG       + 33554432; // 786432*4
static const long O_TBE      = O_UC       + 3145728;  // padded enc_tb (416*4)
static const long O_TBD      = O_TBE      + 2048;     // padded dec_tb (352*4)
static const long WS_TOTAL   = O_TBD      + 2048;

extern "C" void kernel_launch(void* const* d_in, const int* in_sizes, int n_in,
                              void* d_out, int out_size, void* d_ws, size_t ws_size,
                              hipStream_t stream)
{
  const float* x       = (const float*)d_in[0];
  const float* v       = (const float*)d_in[1];
  const float* r       = (const float*)d_in[2];
  const float* eps     = (const float*)d_in[3];
  const float* read_w  = (const float*)d_in[4];
  const float* write_w = (const float*)d_in[5];
  const float* prior_w = (const float*)d_in[6];
  const float* prior_b = (const float*)d_in[7];
  const float* post_w  = (const float*)d_in[8];
  const float* post_b  = (const float*)d_in[9];
  const float* enc_gw  = (const float*)d_in[10];
  const float* enc_gb  = (const float*)d_in[11];
  const float* enc_tw  = (const float*)d_in[12];
  const float* enc_tb  = (const float*)d_in[13];
  const float* dec_gw  = (const float*)d_in[14];
  const float* dec_gb  = (const float*)d_in[15];
  const float* dec_tw  = (const float*)d_in[16];
  const float* dec_tb  = (const float*)d_in[17];
  const float* obs_w   = (const float*)d_in[18];
  const float* obs_b   = (const float*)d_in[19];

  char* ws = (char*)d_ws;
  unsigned char* Bt8Post = (unsigned char*)(ws + O_BT_POST);
  unsigned char* Bt8EncT = (unsigned char*)(ws + O_BT_ENCT);
  unsigned char* Bt8DP   = (unsigned char*)(ws + O_BT_DP);
  unsigned char* Bt8EncG = (unsigned char*)(ws + O_BT_ENCG);
  unsigned char* Bt8DecG = (unsigned char*)(ws + O_BT_DECG);
  float* Wcomb  = (float*)(ws + O_WCOMB);
  float* XR     = (float*)(ws + O_XR);
  float* KLpart = (float*)(ws + O_KLP);
  bf16* STenc   = (bf16*)(ws + O_STENC);
  bf16* STdec   = (bf16*)(ws + O_STDEC);
  bf16* hDec    = (bf16*)(ws + O_HDEC);
  unsigned char* sEnc8 = (unsigned char*)(ws + O_SENC);
  unsigned char* sDec8 = (unsigned char*)(ws + O_SDEC);
  float* cEnc   = (float*)(ws + O_CENC);
  float* cDec   = (float*)(ws + O_CDEC);
  float* PriorO = (float*)(ws + O_PRIOR);
  unsigned char* h8Enc = (unsigned char*)(ws + O_H8E);
  unsigned char* h8Dec = (unsigned char*)(ws + O_H8D);
  bf16* Gates   = (bf16*)(ws + O_PG);
  bf16* PostP   = (bf16*)(ws + O_PG + 16777216);
  float* Ucomb  = (float*)(ws + O_UC);
  float* TBE    = (float*)(ws + O_TBE);
  float* TBD    = (float*)(ws + O_TBD);
  float* out    = (float*)d_out;

  size_t clr = (size_t)WS_TOTAL; if (clr > ws_size) clr = ws_size;
  hipMemsetAsync(d_ws, 0, clr, stream);

  // weight repacks (all fp8, kh-row-grouped) + padded biases
  repack_w8_k<<<1600, 256, 0, stream>>>(post_w, Bt8Post, 128, 128, 128, 5, 128L*3200);
  repack_w8_k<<<6400, 256, 0, stream>>>(enc_tw, Bt8EncT, 394, 128, 128, 5, 512L*3200);
  repack_w8_k<<<4800, 256, 0, stream>>>(dec_tw, Bt8DP, 327, 128, 128, 5, 384L*3200);
  repack_w8_k<<<1600, 256, 0, stream>>>(prior_w, Bt8DP + 384L*3200, 128, 128, 128, 5, 128L*3200);
  repack_w8_k<<<21760, 256, 0, stream>>>(enc_gw, Bt8EncG, 512, 394, 416, 17, 512L*10880);
  repack_w8_k<<<17920, 256, 0, stream>>>(dec_gw, Bt8DecG, 512, 327, 352, 14, 512L*8960);
  padbias_k<<<1, 512, 0, stream>>>(enc_tb, dec_tb, TBE, TBD);
  wcomb_k<<<24, 256, 0, stream>>>(write_w, obs_w, Wcomb);
  xr_k<<<192, 256, 0, stream>>>(x, read_w, XR);
  st_enc_k<<<(int)(((long)MTOT*266 + 255)/256), 256, 0, stream>>>(XR, v, r, STenc);
  st_dec_k<<<(int)(((long)MTOT*263 + 255)/256), 256, 0, stream>>>(v, r, STdec);

  for (int t = 0; t < 8; ++t) {
    // merged fp8 T-convs (decT+prior | encT), vectorized C^T epilogues
    conv_tp8<<<dim3(128,4,2), 256, 0, stream>>>(
        h8Dec, h8Enc, Bt8DP, Bt8EncT, TBD, prior_b, TBE,
        PriorO, sDec8, STdec, sEnc8, STenc, hDec);
    // enc gates: MX-fp8 (coalesced staging, row-grouped K)
    conv_g8<416,17><<<dim3(128,4), 256, 0, stream>>>(sEnc8, Bt8EncG, enc_gb, Gates);
    lstm_k<<<1024, 256, 0, stream>>>(Gates, cEnc, h8Enc);
    // post: MX-fp8 split-K=4 -> bf16 partial planes
    conv_p8<<<dim3(128,1,4), 256, 0, stream>>>(h8Enc, Bt8Post, PostP);
    // z (sum partials + bias) -> add into fp8 sDec ch0..63 ; KL partials
    zkl4_k<<<4096, 256, 0, stream>>>(PostP, post_b, PriorO,
                                     eps + (long)t*64*64*256, sDec8,
                                     KLpart + (long)t*4096);
    // dec gates: MX-fp8
    conv_g8<352,14><<<dim3(128,4), 256, 0, stream>>>(sDec8, Bt8DecG, dec_gb, Gates);
    // dec LSTM + fused canvas accumulate (covers h^1..h^8 over the loop)
    lstm_wrc_k<<<1024, 256, 0, stream>>>(Gates, cDec, hDec, h8Dec, Wcomb, Ucomb);
  }

  canvas_k<<<3072, 256, 0, stream>>>(Ucomb, obs_b, out);
  klred_k<<<1, 256, 0, stream>>>(KLpart, out);
}